// Round 3
// baseline (10262.774 us; speedup 1.0000x reference)
//
#include <hip/hip_runtime.h>
#include <math.h>

static constexpr int NB = 8;    // batch
static constexpr int NT = 10;   // time
static constexpr int E  = 32;   // edge
static constexpr int H1 = 30, W1 = 30, F1 = 256, G1 = 1024; // layer1: gates 4*F1
static constexpr int H2 = 28, W2 = 28, F2 = 128, G2 = 512;  // layer2

__device__ __forceinline__ float sigf(float v){ return 1.0f/(1.0f + __expf(-v)); }

// ---------------- ConvLSTM layer 1, one time step ----------------
// grid = 960 (4 ch-chunks * 30 rows * 8 batch), block 256 = 64 ch * 4 xgroups
// thread computes 4 gates x 8 x-positions for one output channel.
__global__ __launch_bounds__(256)
void l1_step(const float* __restrict__ x, const float* __restrict__ Wx,
             const float* __restrict__ Wh, const float* __restrict__ bias,
             const float* __restrict__ h_in, float* __restrict__ h_out,
             float* __restrict__ c_st, int t, int first)
{
    __shared__ float lds[3*34*64];   // 3 rows x 34 cols (pad -1..32) x 64 ci
    const int bid   = blockIdx.x;
    const int chunk = bid & 3;
    const int y     = (bid >> 2) % H1;
    const int b     = (bid >> 2) / H1;
    const int tid   = threadIdx.x;
    const int cl    = tid & 63;
    const int xg    = tid >> 6;
    const int c     = chunk*64 + cl;   // output channel 0..255
    const int x0    = xg*8;            // x = x0+p, p in 0..7 (mask x<30)

    float acc[4][8];
    #pragma unroll
    for (int g=0; g<4; ++g){
        float bg = bias[g*F1 + c];
        #pragma unroll
        for (int p=0; p<8; ++p) acc[g][p] = bg;
    }

    // input conv (VALID, Cin=1): z += x[b,t,y+dy,x+dx] * Wx[dy,dx,0,co]
    {
        const float* xt = x + ((size_t)b*NT + t)*E*E;
        #pragma unroll
        for (int dy=0; dy<3; ++dy){
            #pragma unroll
            for (int dx=0; dx<3; ++dx){
                const float w0 = Wx[(dy*3+dx)*G1 + 0*F1 + c];
                const float w1 = Wx[(dy*3+dx)*G1 + 1*F1 + c];
                const float w2 = Wx[(dy*3+dx)*G1 + 2*F1 + c];
                const float w3 = Wx[(dy*3+dx)*G1 + 3*F1 + c];
                #pragma unroll
                for (int p=0; p<8; ++p){
                    int xc = x0 + p + dx; if (xc > E-1) xc = E-1; // masked lanes: clamp (discarded)
                    float xv = xt[(y+dy)*E + xc];
                    acc[0][p] += w0*xv; acc[1][p] += w1*xv;
                    acc[2][p] += w2*xv; acc[3][p] += w3*xv;
                }
            }
        }
    }

    // recurrent conv (SAME over h_in), skipped at t==0 (h==0)
    if (!first){
        const float* hp = h_in + (size_t)b*H1*W1*F1;
        for (int cc=0; cc<4; ++cc){           // 4 chunks of 64 input channels
            __syncthreads();
            for (int e = tid; e < 3*34*64; e += 256){
                int ci  = e & 63;
                int col = (e >> 6) % 34;
                int r   = (e >> 6) / 34;
                int gy = y - 1 + r;
                int gx = col - 1;
                float v = 0.0f;
                if (gy >= 0 && gy < H1 && gx >= 0 && gx < W1)
                    v = hp[((size_t)gy*W1 + gx)*F1 + cc*64 + ci];
                lds[e] = v;
            }
            __syncthreads();
            #pragma unroll 1
            for (int k=0; k<9; ++k){
                const int dy = k/3, dx = k%3;
                const float* wrow = Wh + ((size_t)k*F1 + cc*64)*G1 + c;
                const float* hrow = lds + (dy*34 + x0 + dx)*64;  // LDS col = global col + 1
                #pragma unroll 4
                for (int ci=0; ci<64; ++ci){
                    float w0 = wrow[(size_t)ci*G1];
                    float w1 = wrow[(size_t)ci*G1 + F1];
                    float w2 = wrow[(size_t)ci*G1 + 2*F1];
                    float w3 = wrow[(size_t)ci*G1 + 3*F1];
                    #pragma unroll
                    for (int p=0; p<8; ++p){
                        float hv = hrow[p*64 + ci];
                        acc[0][p] += w0*hv;
                        acc[1][p] += w1*hv;
                        acc[2][p] += w2*hv;
                        acc[3][p] += w3*hv;
                    }
                }
            }
        }
    }

    float* co = c_st  + ((size_t)b*H1 + y)*W1*F1;
    float* ho = h_out + ((size_t)b*H1 + y)*W1*F1;
    #pragma unroll
    for (int p=0; p<8; ++p){
        int xp = x0 + p;
        if (xp < W1){
            size_t idx = (size_t)xp*F1 + c;
            float iv = sigf(acc[0][p]);
            float fv = sigf(acc[1][p]);
            float gv = tanhf(acc[2][p]);
            float ov = sigf(acc[3][p]);
            float cp = first ? 0.0f : co[idx];
            float cn = fv*cp + iv*gv;
            co[idx] = cn;
            ho[idx] = ov*tanhf(cn);
        }
    }
}

// ---------------- ConvLSTM layer 2, one time step ----------------
// grid = 448 (2 ch-chunks * 28 rows * 8 batch), block 256 = 64 ch * 4 xg, P=7
__global__ __launch_bounds__(256)
void l2_step(const float* __restrict__ h1, const float* __restrict__ Wx,
             const float* __restrict__ Wh, const float* __restrict__ bias,
             const float* __restrict__ h_in, float* __restrict__ h_out,
             float* __restrict__ c_st, int first)
{
    __shared__ float lds[3*30*64];
    const int bid   = blockIdx.x;
    const int chunk = bid & 1;
    const int y     = (bid >> 1) % H2;
    const int b     = (bid >> 1) / H2;
    const int tid   = threadIdx.x;
    const int cl    = tid & 63;
    const int xg    = tid >> 6;
    const int c     = chunk*64 + cl;   // 0..127
    const int x0    = xg*7;            // x = x0+p, p in 0..6 (28 = 4*7, no mask)

    float acc[4][7];
    #pragma unroll
    for (int g=0; g<4; ++g){
        float bg = bias[g*F2 + c];
        #pragma unroll
        for (int p=0; p<7; ++p) acc[g][p] = bg;
    }

    // input conv (VALID over h1: 30x30x256)
    {
        const float* hp = h1 + (size_t)b*H1*W1*F1;
        for (int cc=0; cc<4; ++cc){
            __syncthreads();
            for (int e = tid; e < 3*30*64; e += 256){
                int ci  = e & 63;
                int col = (e >> 6) % 30;
                int r   = (e >> 6) / 30;
                lds[e] = hp[((size_t)(y+r)*W1 + col)*F1 + cc*64 + ci];
            }
            __syncthreads();
            #pragma unroll 1
            for (int k=0; k<9; ++k){
                const int dy = k/3, dx = k%3;
                const float* wrow = Wx + ((size_t)k*F1 + cc*64)*G2 + c;
                const float* hrow = lds + (dy*30 + x0 + dx)*64;  // LDS col = global col
                #pragma unroll 4
                for (int ci=0; ci<64; ++ci){
                    float w0 = wrow[(size_t)ci*G2];
                    float w1 = wrow[(size_t)ci*G2 + F2];
                    float w2 = wrow[(size_t)ci*G2 + 2*F2];
                    float w3 = wrow[(size_t)ci*G2 + 3*F2];
                    #pragma unroll
                    for (int p=0; p<7; ++p){
                        float hv = hrow[p*64 + ci];
                        acc[0][p] += w0*hv;
                        acc[1][p] += w1*hv;
                        acc[2][p] += w2*hv;
                        acc[3][p] += w3*hv;
                    }
                }
            }
        }
    }

    // recurrent conv (SAME over h_in: 28x28x128), skipped at t==0
    if (!first){
        const float* hp = h_in + (size_t)b*H2*W2*F2;
        for (int cc=0; cc<2; ++cc){
            __syncthreads();
            for (int e = tid; e < 3*30*64; e += 256){
                int ci  = e & 63;
                int col = (e >> 6) % 30;
                int r   = (e >> 6) / 30;
                int gy = y - 1 + r;
                int gx = col - 1;
                float v = 0.0f;
                if (gy >= 0 && gy < H2 && gx >= 0 && gx < W2)
                    v = hp[((size_t)gy*W2 + gx)*F2 + cc*64 + ci];
                lds[e] = v;
            }
            __syncthreads();
            #pragma unroll 1
            for (int k=0; k<9; ++k){
                const int dy = k/3, dx = k%3;
                const float* wrow = Wh + ((size_t)k*F2 + cc*64)*G2 + c;
                const float* hrow = lds + (dy*30 + x0 + dx)*64;  // LDS col = global col + 1
                #pragma unroll 4
                for (int ci=0; ci<64; ++ci){
                    float w0 = wrow[(size_t)ci*G2];
                    float w1 = wrow[(size_t)ci*G2 + F2];
                    float w2 = wrow[(size_t)ci*G2 + 2*F2];
                    float w3 = wrow[(size_t)ci*G2 + 3*F2];
                    #pragma unroll
                    for (int p=0; p<7; ++p){
                        float hv = hrow[p*64 + ci];
                        acc[0][p] += w0*hv;
                        acc[1][p] += w1*hv;
                        acc[2][p] += w2*hv;
                        acc[3][p] += w3*hv;
                    }
                }
            }
        }
    }

    float* co = c_st  + ((size_t)b*H2 + y)*W2*F2;
    float* ho = h_out + ((size_t)b*H2 + y)*W2*F2;
    #pragma unroll
    for (int p=0; p<7; ++p){
        int xp = x0 + p;
        size_t idx = (size_t)xp*F2 + c;
        float iv = sigf(acc[0][p]);
        float fv = sigf(acc[1][p]);
        float gv = tanhf(acc[2][p]);
        float ov = sigf(acc[3][p]);
        float cp = first ? 0.0f : co[idx];
        float cn = fv*cp + iv*gv;
        co[idx] = cn;
        ho[idx] = ov*tanhf(cn);
    }
}

// ---------------- dense head / fcs ----------------
// dense1: (6272,128) @ (128,256) + b, relu.  one block per row.
__global__ __launch_bounds__(256)
void dense1_k(const float* __restrict__ h2, const float* __restrict__ W,
              const float* __restrict__ bv, float* __restrict__ out)
{
    __shared__ float row[F2];
    int r = blockIdx.x;
    int j = threadIdx.x;
    if (j < F2) row[j] = h2[(size_t)r*F2 + j];
    __syncthreads();
    float s = bv[j];
    #pragma unroll 8
    for (int k=0; k<F2; ++k) s += row[k]*W[(size_t)k*256 + j];
    out[(size_t)r*256 + j] = s > 0.f ? s : 0.f;
}

// dense2: (6272,256) @ (256,64) + b, relu -> writes into concat buffer rows 0..27
__global__ __launch_bounds__(256)
void dense2_k(const float* __restrict__ in, const float* __restrict__ W,
              const float* __restrict__ bv, float* __restrict__ cat)
{
    int tid = threadIdx.x;
    int j  = tid & 63;
    int rl = tid >> 6;
    int r = blockIdx.x*4 + rl;   // 0..6271
    const float* irow = in + (size_t)r*256;
    float s = bv[j];
    #pragma unroll 8
    for (int k=0; k<256; ++k) s += irow[k]*W[(size_t)k*64 + j];
    int b   = r / (H2*W2);
    int rem = r % (H2*W2);
    int yy  = rem / W2;
    int xx  = rem % W2;
    float v = s > 0.f ? s : 0.f;
    cat[(((size_t)b*30 + yy)*W2 + xx)*64 + j] = v;
}

// copy t,loc into concat rows 28,29
__global__ void copy_tl_k(const float* __restrict__ tin, const float* __restrict__ lin,
                          float* __restrict__ cat)
{
    int i = blockIdx.x*blockDim.x + threadIdx.x;
    const int n = NB*W2*64;   // 14336
    if (i < 2*n){
        const float* src = (i < n) ? tin : lin;
        int ii   = (i < n) ? i : i - n;
        int yrow = (i < n) ? 28 : 29;
        int b    = ii / (W2*64);
        int rem  = ii % (W2*64);
        cat[(((size_t)b*30 + yrow)*W2)*64 + rem] = src[ii];
    }
}

// fc1: (6720,64) @ (64,64) + b, relu
__global__ __launch_bounds__(256)
void fc1_k(const float* __restrict__ in, const float* __restrict__ W,
           const float* __restrict__ bv, float* __restrict__ out)
{
    int tid = threadIdx.x;
    int j  = tid & 63;
    int rl = tid >> 6;
    int r = blockIdx.x*4 + rl;   // 0..6719
    const float* irow = in + (size_t)r*64;
    float s = bv[j];
    #pragma unroll 8
    for (int k=0; k<64; ++k) s += irow[k]*W[(size_t)k*64 + j];
    out[(size_t)r*64 + j] = s > 0.f ? s : 0.f;
}

// fc2: (6720,64) @ (64,1) + b  -> d_out. one wave per row.
__global__ __launch_bounds__(256)
void fc2_k(const float* __restrict__ in, const float* __restrict__ W,
           const float* __restrict__ bv, float* __restrict__ out)
{
    int tid  = threadIdx.x;
    int lane = tid & 63;
    int r = blockIdx.x*4 + (tid >> 6);
    float v = in[(size_t)r*64 + lane] * W[lane];
    #pragma unroll
    for (int s=32; s>0; s>>=1) v += __shfl_down(v, s, 64);
    if (lane == 0) out[r] = v + bv[0];
}

extern "C" void kernel_launch(void* const* d_in, const int* in_sizes, int n_in,
                              void* d_out, int out_size, void* d_ws, size_t ws_size,
                              hipStream_t stream)
{
    (void)in_sizes; (void)n_in; (void)out_size; (void)ws_size;
    const float* x   = (const float*)d_in[0];
    const float* tin = (const float*)d_in[1];
    const float* lin = (const float*)d_in[2];
    const float* Wx1 = (const float*)d_in[3];
    const float* Wh1 = (const float*)d_in[4];
    const float* b1  = (const float*)d_in[5];
    const float* Wx2 = (const float*)d_in[6];
    const float* Wh2 = (const float*)d_in[7];
    const float* b2  = (const float*)d_in[8];
    const float* Wd1 = (const float*)d_in[9];
    const float* bd1 = (const float*)d_in[10];
    const float* Wd2 = (const float*)d_in[11];
    const float* bd2 = (const float*)d_in[12];
    const float* Wf1 = (const float*)d_in[13];
    const float* bf1 = (const float*)d_in[14];
    const float* Wf2 = (const float*)d_in[15];
    const float* bf2 = (const float*)d_in[16];
    float* out = (float*)d_out;

    // workspace layout (floats). Head-phase buffers alias layer-1 state
    // buffers (dead after the time loop) to keep footprint at
    // 3*szH1 + 3*szH2 = 7,938,048 floats ~= 31.8 MB.
    const size_t szH1 = (size_t)NB*H1*W1*F1;  // 1,843,200
    const size_t szH2 = (size_t)NB*H2*W2*F2;  //   802,816
    float* ws  = (float*)d_ws;
    float* h1a = ws;
    float* h1b = h1a + szH1;
    float* c1  = h1b + szH1;
    float* h2a = c1  + szH1;
    float* h2b = h2a + szH2;
    float* c2  = h2b + szH2;
    float* d1o = h1a;   // 6272*256 = 1,605,632 <= szH1
    float* cat = h1b;   // 8*30*28*64 = 430,080 <= szH1
    float* f1o = c1;    // 6720*64   = 430,080 <= szH1

    for (int t=0; t<NT; ++t){
        const float* h1in = (t & 1) ? h1b : h1a;
        float*       h1out= (t & 1) ? h1a : h1b;
        l1_step<<<960, 256, 0, stream>>>(x, Wx1, Wh1, b1, h1in, h1out, c1, t, t==0);
        const float* h2in = (t & 1) ? h2b : h2a;
        float*       h2out= (t & 1) ? h2a : h2b;
        l2_step<<<448, 256, 0, stream>>>(h1out, Wx2, Wh2, b2, h2in, h2out, c2, t==0);
    }
    // t=9 (odd) wrote h2a
    dense1_k<<<6272, 256, 0, stream>>>(h2a, Wd1, bd1, d1o);
    dense2_k<<<1568, 256, 0, stream>>>(d1o, Wd2, bd2, cat);
    copy_tl_k<<<(2*NB*W2*64 + 255)/256, 256, 0, stream>>>(tin, lin, cat);
    fc1_k<<<1680, 256, 0, stream>>>(cat, Wf1, bf1, f1o);
    fc2_k<<<1680, 256, 0, stream>>>(f1o, Wf2, bf2, out);
}

// Round 5
// 1964.285 us; speedup vs baseline: 5.2247x; 5.2247x over previous
//
#include <hip/hip_runtime.h>
#include <math.h>

static constexpr int NB = 8, NT = 10, E = 32;
static constexpr int H1 = 30, W1 = 30, F1 = 256, G1 = 1024;
static constexpr int H2 = 28, W2 = 28, F2 = 128, G2 = 512;

typedef _Float16 half8 __attribute__((ext_vector_type(8)));
typedef float f32x4 __attribute__((ext_vector_type(4)));

__device__ __forceinline__ float sigf(float v){ return 1.0f/(1.0f + __expf(-v)); }

// ---------- weight prep: fp32 [tap][ci][gate] -> fp16 [tap][gate][ci] ----------
__global__ __launch_bounds__(256)
void prep_w(const float* __restrict__ Wh1, const float* __restrict__ Wx2,
            const float* __restrict__ Wh2, _Float16* __restrict__ Wh1t,
            _Float16* __restrict__ Wx2t, _Float16* __restrict__ Wh2t)
{
    int i = blockIdx.x*256 + threadIdx.x;
    if (i < 2359296){                      // Wh1t: (tap*1024+g)*256+ci
        int ci = i & 255, g = (i>>8) & 1023, tap = i>>18;
        Wh1t[i] = (_Float16)Wh1[(tap*256 + ci)*1024 + g];
    } else if (i < 2359296 + 1179648){     // Wx2t: (tap*512+g)*256+ci
        int j = i - 2359296;
        int ci = j & 255, g = (j>>8) & 511, tap = j>>17;
        Wx2t[j] = (_Float16)Wx2[(tap*256 + ci)*512 + g];
    } else if (i < 2359296 + 1179648 + 589824){  // Wh2t: (tap*512+g)*128+ci
        int j = i - (2359296 + 1179648);
        int ci = j & 127, g = (j>>7) & 511, tap = j>>16;
        Wh2t[j] = (_Float16)Wh2[(tap*128 + ci)*512 + g];
    }
}

// ---------- layer-1 t=0 (no recurrent): scalar fp32 ----------
__global__ __launch_bounds__(256)
void l1_t0(const float* __restrict__ x, const float* __restrict__ Wx1,
           const float* __restrict__ b1, _Float16* __restrict__ h_out,
           float* __restrict__ c_st)
{
    const int bid = blockIdx.x;          // 240 = 8*30
    const int y = bid % 30, b = bid / 30;
    const int c = threadIdx.x;           // 0..255
    float wx[9][4], bq[4];
    #pragma unroll
    for (int tp=0; tp<9; ++tp)
        #pragma unroll
        for (int q=0; q<4; ++q) wx[tp][q] = Wx1[tp*G1 + q*F1 + c];
    #pragma unroll
    for (int q=0; q<4; ++q) bq[q] = b1[q*F1 + c];
    const float* xt = x + ((size_t)b*NT)*E*E;   // t=0
    for (int px=0; px<30; ++px){
        float z0=bq[0], z1=bq[1], z2=bq[2], z3=bq[3];
        #pragma unroll
        for (int dy=0; dy<3; ++dy)
            #pragma unroll
            for (int dx=0; dx<3; ++dx){
                float xv = xt[(y+dy)*E + px+dx];
                z0 += xv*wx[dy*3+dx][0]; z1 += xv*wx[dy*3+dx][1];
                z2 += xv*wx[dy*3+dx][2]; z3 += xv*wx[dy*3+dx][3];
            }
        float iv = sigf(z0), gv = tanhf(z2), ov = sigf(z3);
        int idx = ((b*30 + y)*30 + px)*F1 + c;
        float cn = iv*gv;                 // c_prev = 0
        c_st[idx] = cn;
        h_out[idx] = (_Float16)(ov*tanhf(cn));
    }
}

// ---------- layer-1 MFMA step (t>=1) ----------
// grid 480 = 8b * 15 row-pairs * 4 ch-quarters; 256 thr (4 waves)
// wave tile: M=64 (2 rows x 32 px), N=64 (16 ch x 4 gate-quadrants)
__global__ __launch_bounds__(256, 2)
void l1_mfma(const float* __restrict__ x, const _Float16* __restrict__ Wh1t,
             const float* __restrict__ Wx1, const float* __restrict__ b1,
             const _Float16* __restrict__ h_prev, _Float16* __restrict__ h_out,
             float* __restrict__ c_st, int t)
{
    __shared__ _Float16 Alds[4*32*128];   // 32 KB, [r][x][ci128], byte ^ ((x&7)<<4)
    __shared__ _Float16 Blds[2][8192];    // 2x16 KB, [gl][ci32], byte ^ ((gl&7)<<4)

    const int bid = blockIdx.x;
    const int nq  = bid & 3;
    const int tmp = bid >> 2;
    const int rp  = tmp % 15;
    const int b   = tmp / 15;
    const int y0  = rp*2;

    const int tid  = threadIdx.x;
    const int w    = tid >> 6;
    const int lane = tid & 63;
    const int l15  = lane & 15;
    const int l16  = lane >> 4;
    const int c    = nq*64 + w*16 + l15;          // output channel 0..255

    f32x4 acc[4][4];
    #pragma unroll
    for (int mt=0; mt<4; ++mt)
        #pragma unroll
        for (int q=0; q<4; ++q) acc[mt][q] = (f32x4){0.f,0.f,0.f,0.f};

    int boff[4];
    #pragma unroll
    for (int q=0; q<4; ++q){
        int gl = q*64 + w*16 + l15;
        boff[q] = ((gl<<6) + (l16<<4)) ^ ((gl&7)<<4);
    }

    const int gl_s = tid;
    const int sw_s = (tid&7)<<4;
    const int g_glob = (tid>>6)*256 + nq*64 + (tid&63);   // gate row in Wh1t
    uint4 pv0, pv1, pv2, pv3;

    auto loadB = [&](int cih, int tap, int cib){
        const _Float16* src = Wh1t + (((size_t)(tap*1024 + g_glob))<<8) + (cih<<7) + (cib<<5);
        pv0 = *(const uint4*)(const void*)(src);
        pv1 = *(const uint4*)(const void*)(src + 8);
        pv2 = *(const uint4*)(const void*)(src + 16);
        pv3 = *(const uint4*)(const void*)(src + 24);
    };
    auto writeB = [&](int bi){
        char* dst = (char*)Blds + bi*16384;
        *(uint4*)(void*)(dst + (((gl_s<<6) +  0) ^ sw_s)) = pv0;
        *(uint4*)(void*)(dst + (((gl_s<<6) + 16) ^ sw_s)) = pv1;
        *(uint4*)(void*)(dst + (((gl_s<<6) + 32) ^ sw_s)) = pv2;
        *(uint4*)(void*)(dst + (((gl_s<<6) + 48) ^ sw_s)) = pv3;
    };

    for (int cih=0; cih<2; ++cih){
        __syncthreads();
        // stage A half: rows y0-1..y0+2, lds x 0..31 <-> gx -1..30
        #pragma unroll
        for (int it=0; it<8; ++it){
            int e = tid + (it<<8);
            int ci8 = e & 15, xx = (e>>4)&31, r = e>>9;
            int gy = y0 - 1 + r, gx = xx - 1;
            uint4 v = {0u,0u,0u,0u};
            if (gy >= 0 && gy < 30 && gx >= 0 && gx < 30)
                v = *(const uint4*)(const void*)(h_prev + ((((b*30+gy)*30+gx))<<8) + (cih<<7) + (ci8<<3));
            *(uint4*)(void*)((char*)Alds + ((((((r<<5)+xx))<<8) + (ci8<<4)) ^ ((xx&7)<<4))) = v;
        }
        loadB(cih, 0, 0);
        __syncthreads();
        writeB(0);
        __syncthreads();
        int sl = 0;
        for (int dy=0; dy<3; ++dy)
        for (int dx=0; dx<3; ++dx){
            int ab[4], asw[4];
            #pragma unroll
            for (int mt=0; mt<4; ++mt){
                int ax = ((mt&1)<<4) + l15 + dx; if (ax > 31) ax = 31;
                int ar = (mt>>1) + dy;
                ab[mt]  = (((ar<<5)+ax)<<8) + (l16<<4);
                asw[mt] = (ax&7)<<4;
            }
            for (int cib=0; cib<4; ++cib, ++sl){
                int nxt = sl + 1;
                if (nxt < 36) loadB(cih, nxt>>2, nxt&3);
                half8 a[4], bb[4];
                #pragma unroll
                for (int mt=0; mt<4; ++mt)
                    a[mt] = *(const half8*)(const void*)((const char*)Alds + ((ab[mt] + (cib<<6)) ^ asw[mt]));
                const char* bp = (const char*)Blds + (sl&1)*16384;
                #pragma unroll
                for (int q=0; q<4; ++q)
                    bb[q] = *(const half8*)(const void*)(bp + boff[q]);
                #pragma unroll
                for (int mt=0; mt<4; ++mt)
                    #pragma unroll
                    for (int q=0; q<4; ++q)
                        acc[mt][q] = __builtin_amdgcn_mfma_f32_16x16x32_f16(a[mt], bb[q], acc[mt][q], 0, 0, 0);
                if (nxt < 36) writeB(nxt&1);
                __syncthreads();
            }
        }
    }

    // epilogue: + x-conv (fp32 exact) + bias -> gates -> c,h
    float wx[9][4], bq[4];
    #pragma unroll
    for (int tp=0; tp<9; ++tp)
        #pragma unroll
        for (int q=0; q<4; ++q) wx[tp][q] = Wx1[tp*G1 + q*F1 + c];
    #pragma unroll
    for (int q=0; q<4; ++q) bq[q] = b1[q*F1 + c];
    const float* xt = x + ((size_t)(b*NT + t))*E*E;
    #pragma unroll
    for (int mt=0; mt<4; ++mt){
        int py = mt>>1;
        int pxb = ((mt&1)<<4) + (l16<<2);
        int yo = y0 + py;
        #pragma unroll
        for (int r=0; r<4; ++r){
            int px = pxb + r;
            if (px < 30){
                float z0 = acc[mt][0][r] + bq[0];
                float z1 = acc[mt][1][r] + bq[1];
                float z2 = acc[mt][2][r] + bq[2];
                float z3 = acc[mt][3][r] + bq[3];
                #pragma unroll
                for (int dy=0; dy<3; ++dy)
                    #pragma unroll
                    for (int dx=0; dx<3; ++dx){
                        float xv = xt[(yo+dy)*E + px+dx];
                        z0 += xv*wx[dy*3+dx][0]; z1 += xv*wx[dy*3+dx][1];
                        z2 += xv*wx[dy*3+dx][2]; z3 += xv*wx[dy*3+dx][3];
                    }
                float iv = sigf(z0), fv = sigf(z1), gv = tanhf(z2), ov = sigf(z3);
                int idx = ((b*30 + yo)*30 + px)*F1 + c;
                float cn = fv*c_st[idx] + iv*gv;
                c_st[idx] = cn;
                h_out[idx] = (_Float16)(ov*tanhf(cn));
            }
        }
    }
}

// ---------- layer-2 MFMA step (t>=0; first => skip recurrent) ----------
// grid 448 = 8b * 28 rows * 2 ch-halves; 256 thr (4 waves)
// wave tile: M=32 (1 row x 32 px), N=64 (16 ch x 4 gate-quadrants)
__global__ __launch_bounds__(256, 2)
void l2_mfma(const _Float16* __restrict__ h1, const _Float16* __restrict__ Wx2t,
             const _Float16* __restrict__ Wh2t, const float* __restrict__ b2,
             const _Float16* __restrict__ h2prev, _Float16* __restrict__ h2out,
             float* __restrict__ c_st, int first)
{
    __shared__ _Float16 Alds[3*32*128];   // 24 KB
    __shared__ _Float16 Blds[2][8192];    // 32 KB

    const int bid = blockIdx.x;
    const int nh  = bid & 1;
    const int tmp = bid >> 1;
    const int y0  = tmp % 28;
    const int b   = tmp / 28;

    const int tid  = threadIdx.x;
    const int w    = tid >> 6;
    const int lane = tid & 63;
    const int l15  = lane & 15;
    const int l16  = lane >> 4;
    const int c    = nh*64 + w*16 + l15;          // output channel 0..127

    f32x4 acc[2][4];
    #pragma unroll
    for (int mt=0; mt<2; ++mt)
        #pragma unroll
        for (int q=0; q<4; ++q) acc[mt][q] = (f32x4){0.f,0.f,0.f,0.f};

    int boff[4];
    #pragma unroll
    for (int q=0; q<4; ++q){
        int gl = q*64 + w*16 + l15;
        boff[q] = ((gl<<6) + (l16<<4)) ^ ((gl&7)<<4);
    }
    const int gl_s = tid;
    const int sw_s = (tid&7)<<4;
    const int g_glob = (tid>>6)*128 + nh*64 + (tid&63);   // gate row (0..511)
    uint4 pv0, pv1, pv2, pv3;

    auto loadB1 = [&](int cih, int tap, int cib){
        const _Float16* src = Wx2t + (((size_t)(tap*512 + g_glob))<<8) + (cih<<7) + (cib<<5);
        pv0 = *(const uint4*)(const void*)(src);
        pv1 = *(const uint4*)(const void*)(src + 8);
        pv2 = *(const uint4*)(const void*)(src + 16);
        pv3 = *(const uint4*)(const void*)(src + 24);
    };
    auto loadB2 = [&](int tap, int cib){
        const _Float16* src = Wh2t + (((size_t)(tap*512 + g_glob))<<7) + (cib<<5);
        pv0 = *(const uint4*)(const void*)(src);
        pv1 = *(const uint4*)(const void*)(src + 8);
        pv2 = *(const uint4*)(const void*)(src + 16);
        pv3 = *(const uint4*)(const void*)(src + 24);
    };
    auto writeB = [&](int bi){
        char* dst = (char*)Blds + bi*16384;
        *(uint4*)(void*)(dst + (((gl_s<<6) +  0) ^ sw_s)) = pv0;
        *(uint4*)(void*)(dst + (((gl_s<<6) + 16) ^ sw_s)) = pv1;
        *(uint4*)(void*)(dst + (((gl_s<<6) + 32) ^ sw_s)) = pv2;
        *(uint4*)(void*)(dst + (((gl_s<<6) + 48) ^ sw_s)) = pv3;
    };

    // ---- phase 1: input conv (VALID) over h1, K = 2 cih * 9 taps * 4 cib ----
    for (int cih=0; cih<2; ++cih){
        __syncthreads();
        #pragma unroll
        for (int it=0; it<6; ++it){
            int e = tid + (it<<8);
            int ci8 = e & 15, xx = (e>>4)&31, r = e>>9;
            int gy = y0 + r, gx = xx;
            uint4 v = {0u,0u,0u,0u};
            if (gx < 30)
                v = *(const uint4*)(const void*)(h1 + ((((b*30+gy)*30+gx))<<8) + (cih<<7) + (ci8<<3));
            *(uint4*)(void*)((char*)Alds + ((((((r<<5)+xx))<<8) + (ci8<<4)) ^ ((xx&7)<<4))) = v;
        }
        loadB1(cih, 0, 0);
        __syncthreads();
        writeB(0);
        __syncthreads();
        int sl = 0;
        for (int dy=0; dy<3; ++dy)
        for (int dx=0; dx<3; ++dx){
            int ab[2], asw[2];
            #pragma unroll
            for (int mt=0; mt<2; ++mt){
                int ax = (mt<<4) + l15 + dx; if (ax > 31) ax = 31;
                ab[mt]  = (((dy<<5)+ax)<<8) + (l16<<4);
                asw[mt] = (ax&7)<<4;
            }
            for (int cib=0; cib<4; ++cib, ++sl){
                int nxt = sl + 1;
                if (nxt < 36) loadB1(cih, nxt>>2, nxt&3);
                half8 a[2], bb[4];
                #pragma unroll
                for (int mt=0; mt<2; ++mt)
                    a[mt] = *(const half8*)(const void*)((const char*)Alds + ((ab[mt] + (cib<<6)) ^ asw[mt]));
                const char* bp = (const char*)Blds + (sl&1)*16384;
                #pragma unroll
                for (int q=0; q<4; ++q)
                    bb[q] = *(const half8*)(const void*)(bp + boff[q]);
                #pragma unroll
                for (int mt=0; mt<2; ++mt)
                    #pragma unroll
                    for (int q=0; q<4; ++q)
                        acc[mt][q] = __builtin_amdgcn_mfma_f32_16x16x32_f16(a[mt], bb[q], acc[mt][q], 0, 0, 0);
                if (nxt < 36) writeB(nxt&1);
                __syncthreads();
            }
        }
    }

    // ---- phase 2: recurrent conv (SAME) over h2prev, K = 9 taps * 4 cib ----
    if (!first){
        __syncthreads();
        #pragma unroll
        for (int it=0; it<6; ++it){
            int e = tid + (it<<8);
            int ci8 = e & 15, xx = (e>>4)&31, r = e>>9;
            int gy = y0 - 1 + r, gx = xx - 1;
            uint4 v = {0u,0u,0u,0u};
            if (gy >= 0 && gy < 28 && gx >= 0 && gx < 28)
                v = *(const uint4*)(const void*)(h2prev + ((((b*28+gy)*28+gx))<<7) + (ci8<<3));
            *(uint4*)(void*)((char*)Alds + ((((((r<<5)+xx))<<8) + (ci8<<4)) ^ ((xx&7)<<4))) = v;
        }
        loadB2(0, 0);
        __syncthreads();
        writeB(0);
        __syncthreads();
        int sl = 0;
        for (int dy=0; dy<3; ++dy)
        for (int dx=0; dx<3; ++dx){
            int ab[2], asw[2];
            #pragma unroll
            for (int mt=0; mt<2; ++mt){
                int ax = (mt<<4) + l15 + dx; if (ax > 31) ax = 31;
                ab[mt]  = (((dy<<5)+ax)<<8) + (l16<<4);
                asw[mt] = (ax&7)<<4;
            }
            for (int cib=0; cib<4; ++cib, ++sl){
                int nxt = sl + 1;
                if (nxt < 36) loadB2(nxt>>2, nxt&3);
                half8 a[2], bb[4];
                #pragma unroll
                for (int mt=0; mt<2; ++mt)
                    a[mt] = *(const half8*)(const void*)((const char*)Alds + ((ab[mt] + (cib<<6)) ^ asw[mt]));
                const char* bp = (const char*)Blds + (sl&1)*16384;
                #pragma unroll
                for (int q=0; q<4; ++q)
                    bb[q] = *(const half8*)(const void*)(bp + boff[q]);
                #pragma unroll
                for (int mt=0; mt<2; ++mt)
                    #pragma unroll
                    for (int q=0; q<4; ++q)
                        acc[mt][q] = __builtin_amdgcn_mfma_f32_16x16x32_f16(a[mt], bb[q], acc[mt][q], 0, 0, 0);
                if (nxt < 36) writeB(nxt&1);
                __syncthreads();
            }
        }
    }

    // epilogue
    float bq[4];
    #pragma unroll
    for (int q=0; q<4; ++q) bq[q] = b2[q*F2 + c];
    #pragma unroll
    for (int mt=0; mt<2; ++mt){
        #pragma unroll
        for (int r=0; r<4; ++r){
            int px = (mt<<4) + (l16<<2) + r;
            if (px < 28){
                float z0 = acc[mt][0][r] + bq[0];
                float z1 = acc[mt][1][r] + bq[1];
                float z2 = acc[mt][2][r] + bq[2];
                float z3 = acc[mt][3][r] + bq[3];
                float iv = sigf(z0), fv = sigf(z1), gv = tanhf(z2), ov = sigf(z3);
                int idx = ((b*28 + y0)*28 + px)*F2 + c;
                float cold = first ? 0.0f : c_st[idx];
                float cn = fv*cold + iv*gv;
                c_st[idx] = cn;
                h2out[idx] = (_Float16)(ov*tanhf(cn));
            }
        }
    }
}

// ---------------- dense head / fcs ----------------
__global__ __launch_bounds__(256)
void dense1_k(const _Float16* __restrict__ h2, const float* __restrict__ W,
              const float* __restrict__ bv, float* __restrict__ out)
{
    __shared__ float row[F2];
    int r = blockIdx.x;
    int j = threadIdx.x;
    if (j < F2) row[j] = (float)h2[(size_t)r*F2 + j];
    __syncthreads();
    float s = bv[j];
    #pragma unroll 8
    for (int k=0; k<F2; ++k) s += row[k]*W[(size_t)k*256 + j];
    out[(size_t)r*256 + j] = s > 0.f ? s : 0.f;
}

__global__ __launch_bounds__(256)
void dense2_k(const float* __restrict__ in, const float* __restrict__ W,
              const float* __restrict__ bv, float* __restrict__ cat)
{
    int tid = threadIdx.x;
    int j  = tid & 63;
    int rl = tid >> 6;
    int r = blockIdx.x*4 + rl;
    const float* irow = in + (size_t)r*256;
    float s = bv[j];
    #pragma unroll 8
    for (int k=0; k<256; ++k) s += irow[k]*W[(size_t)k*64 + j];
    int b   = r / (H2*W2);
    int rem = r % (H2*W2);
    int yy  = rem / W2;
    int xx  = rem % W2;
    float v = s > 0.f ? s : 0.f;
    cat[(((size_t)b*30 + yy)*W2 + xx)*64 + j] = v;
}

__global__ void copy_tl_k(const float* __restrict__ tin, const float* __restrict__ lin,
                          float* __restrict__ cat)
{
    int i = blockIdx.x*blockDim.x + threadIdx.x;
    const int n = NB*W2*64;
    if (i < 2*n){
        const float* src = (i < n) ? tin : lin;
        int ii   = (i < n) ? i : i - n;
        int yrow = (i < n) ? 28 : 29;
        int b    = ii / (W2*64);
        int rem  = ii % (W2*64);
        cat[(((size_t)b*30 + yrow)*W2)*64 + rem] = src[ii];
    }
}

__global__ __launch_bounds__(256)
void fc1_k(const float* __restrict__ in, const float* __restrict__ W,
           const float* __restrict__ bv, float* __restrict__ out)
{
    int tid = threadIdx.x;
    int j  = tid & 63;
    int rl = tid >> 6;
    int r = blockIdx.x*4 + rl;
    const float* irow = in + (size_t)r*64;
    float s = bv[j];
    #pragma unroll 8
    for (int k=0; k<64; ++k) s += irow[k]*W[(size_t)k*64 + j];
    out[(size_t)r*64 + j] = s > 0.f ? s : 0.f;
}

__global__ __launch_bounds__(256)
void fc2_k(const float* __restrict__ in, const float* __restrict__ W,
           const float* __restrict__ bv, float* __restrict__ out)
{
    int tid  = threadIdx.x;
    int lane = tid & 63;
    int r = blockIdx.x*4 + (tid >> 6);
    float v = in[(size_t)r*64 + lane] * W[lane];
    #pragma unroll
    for (int s=32; s>0; s>>=1) v += __shfl_down(v, s, 64);
    if (lane == 0) out[r] = v + bv[0];
}

extern "C" void kernel_launch(void* const* d_in, const int* in_sizes, int n_in,
                              void* d_out, int out_size, void* d_ws, size_t ws_size,
                              hipStream_t stream)
{
    (void)in_sizes; (void)n_in; (void)out_size; (void)ws_size;
    const float* x   = (const float*)d_in[0];
    const float* tin = (const float*)d_in[1];
    const float* lin = (const float*)d_in[2];
    const float* Wx1 = (const float*)d_in[3];
    const float* Wh1 = (const float*)d_in[4];
    const float* b1  = (const float*)d_in[5];
    const float* Wx2 = (const float*)d_in[6];
    const float* Wh2 = (const float*)d_in[7];
    const float* b2  = (const float*)d_in[8];
    const float* Wd1 = (const float*)d_in[9];
    const float* bd1 = (const float*)d_in[10];
    const float* Wd2 = (const float*)d_in[11];
    const float* bd2 = (const float*)d_in[12];
    const float* Wf1 = (const float*)d_in[13];
    const float* bf1 = (const float*)d_in[14];
    const float* Wf2 = (const float*)d_in[15];
    const float* bf2 = (const float*)d_in[16];
    float* out = (float*)d_out;

    // workspace layout (bytes), total 29,425,664 B
    char* p = (char*)d_ws;
    _Float16* h1a  = (_Float16*)p; p += 3686400;
    _Float16* h1b  = (_Float16*)p; p += 3686400;
    float*    c1   = (float*)p;    p += 7372800;
    _Float16* h2a  = (_Float16*)p; p += 1605632;
    _Float16* h2b  = (_Float16*)p; p += 1605632;
    float*    c2   = (float*)p;    p += 3211264;
    _Float16* Wh1t = (_Float16*)p; p += 4718592;
    _Float16* Wx2t = (_Float16*)p; p += 2359296;
    _Float16* Wh2t = (_Float16*)p; p += 1179648;
    // head buffers alias dead LSTM state
    float* d1o = c1;            // 6272*256 fp32 = 6.42 MB <= 7.37 MB
    float* cat = (float*)h1a;   // 430080 fp32 = 1.72 MB <= 3.69 MB
    float* f1o = (float*)h1b;   // 1.72 MB <= 3.69 MB

    _Float16* h1w[2] = {h1a, h1b};
    _Float16* h2w[2] = {h2a, h2b};

    prep_w<<<16128, 256, 0, stream>>>(Wh1, Wx2, Wh2, Wh1t, Wx2t, Wh2t);
    l1_t0<<<240, 256, 0, stream>>>(x, Wx1, b1, h1w[0], c1);
    l2_mfma<<<448, 256, 0, stream>>>(h1w[0], Wx2t, Wh2t, b2, h2w[0], h2w[0], c2, 1);
    for (int t=1; t<NT; ++t){
        l1_mfma<<<480, 256, 0, stream>>>(x, Wh1t, Wx1, b1, h1w[(t-1)&1], h1w[t&1], c1, t);
        l2_mfma<<<448, 256, 0, stream>>>(h1w[t&1], Wx2t, Wh2t, b2, h2w[(t-1)&1], h2w[t&1], c2, 0);
    }
    // t=9 wrote h2w[1]
    dense1_k<<<6272, 256, 0, stream>>>(h2w[1], Wd1, bd1, d1o);
    dense2_k<<<1568, 256, 0, stream>>>(d1o, Wd2, bd2, cat);
    copy_tl_k<<<(2*NB*W2*64 + 255)/256, 256, 0, stream>>>(tin, lin, cat);
    fc1_k<<<1680, 256, 0, stream>>>(cat, Wf1, bf1, f1o);
    fc2_k<<<1680, 256, 0, stream>>>(f1o, Wf2, bf2, out);
}